// Round 4
// baseline (336.566 us; speedup 1.0000x reference)
//
#include <hip/hip_runtime.h>

typedef unsigned short u16;
typedef __bf16 bf16x8 __attribute__((ext_vector_type(8)));
typedef float f32x4 __attribute__((ext_vector_type(4)));

static constexpr int BB = 16;    // batch
static constexpr int CC = 512;   // channels
static constexpr int SS = 1024;  // seq
static constexpr int R  = 256;   // q-chunk rows (small-ws fallback path)

__device__ __forceinline__ u16 f2bf(float f) {
  __bf16 h = (__bf16)f; return __builtin_bit_cast(unsigned short, h);
}
__device__ __forceinline__ float bf2f(u16 u) {
  union { unsigned int i; float f; } v; v.i = ((unsigned int)u) << 16; return v.f;
}
__device__ __forceinline__ void split2(float v, u16& hi, u16& lo) {
  __bf16 h = (__bf16)v;
  float hf = (float)h;
  __bf16 l = (__bf16)(v - hf);
  hi = __builtin_bit_cast(unsigned short, h);
  lo = __builtin_bit_cast(unsigned short, l);
}

// async global->LDS, 16B per lane; LDS dest = wave-uniform base + lane*16
__device__ __forceinline__ void gld16(const u16* g, u16* l) {
  __builtin_amdgcn_global_load_lds(
      (const __attribute__((address_space(1))) void*)g,
      (__attribute__((address_space(3))) void*)l, 16, 0, 0);
}

// counted vmcnt wait with compile-time literal (T4)
template <int N>
__device__ __forceinline__ void wait_vmcnt() {
  if constexpr (N == 0) asm volatile("s_waitcnt vmcnt(0)" ::: "memory");
  else if constexpr (N == 1) asm volatile("s_waitcnt vmcnt(1)" ::: "memory");
  else if constexpr (N == 2) asm volatile("s_waitcnt vmcnt(2)" ::: "memory");
  else if constexpr (N == 3) asm volatile("s_waitcnt vmcnt(3)" ::: "memory");
  else if constexpr (N == 4) asm volatile("s_waitcnt vmcnt(4)" ::: "memory");
  else if constexpr (N == 5) asm volatile("s_waitcnt vmcnt(5)" ::: "memory");
  else if constexpr (N == 6) asm volatile("s_waitcnt vmcnt(6)" ::: "memory");
  else if constexpr (N == 7) asm volatile("s_waitcnt vmcnt(7)" ::: "memory");
  else asm volatile("s_waitcnt vmcnt(8)" ::: "memory");
}

// bijective XCD-chunked remap of a 3D grid (requires nwg % 8 == 0; all our grids satisfy)
__device__ __forceinline__ void xcd_remap(int& bx, int& by, int& bz) {
  int gx = gridDim.x, gy = gridDim.y;
  int nwg = gx * gy * gridDim.z;
  int flat = (blockIdx.z * gy + blockIdx.y) * gx + blockIdx.x;
  int swz = ((nwg & 7) == 0) ? (flat & 7) * (nwg >> 3) + (flat >> 3) : flat;
  bx = swz % gx;
  int t1 = swz / gx;
  by = t1 % gy;
  bz = t1 / gy;
}

// ---------------- BatchNorm stats per channel over (B,S), fp64 ----------------
__global__ __launch_bounds__(256) void bn_stats_f64(const float* __restrict__ x, double* __restrict__ stats) {
  const int c = blockIdx.x;
  double s = 0.0, s2 = 0.0;
  for (int n = threadIdx.x; n < BB * SS; n += 256) {
    int b = n >> 10, sp = n & (SS - 1);
    double v = (double)x[((long long)(b * CC + c)) * SS + sp];
    s += v; s2 += v * v;
  }
  __shared__ double sh[256], sh2[256];
  sh[threadIdx.x] = s; sh2[threadIdx.x] = s2;
  __syncthreads();
  for (int off = 128; off > 0; off >>= 1) {
    if (threadIdx.x < off) { sh[threadIdx.x] += sh[threadIdx.x + off]; sh2[threadIdx.x] += sh2[threadIdx.x + off]; }
    __syncthreads();
  }
  if (threadIdx.x == 0) {
    double mean = sh[0] / 16384.0;
    double var = sh2[0] / 16384.0 - mean * mean;   // biased (torch BN)
    stats[c] = mean;
    stats[CC + c] = 1.0 / sqrt(var + 1e-5);
  }
}

// ---------------- normalize + transpose + split: x [b,c,s] -> xnh/xnl bf16 [b*S + s][c] ----------------
__global__ __launch_bounds__(256) void bn_apply_split(const float* __restrict__ x,
                                                      const double* __restrict__ stats,
                                                      u16* __restrict__ xnh, u16* __restrict__ xnl) {
  __shared__ float tile[64][65];
  const int b = blockIdx.z;
  const int s0 = blockIdx.x * 64, c0 = blockIdx.y * 64;
  const int t = threadIdx.x & 63, rb = threadIdx.x >> 6;
#pragma unroll
  for (int r0 = 0; r0 < 64; r0 += 4) {
    int r = r0 + rb;
    int c = c0 + r;
    double v = (double)x[((long long)(b * CC + c)) * SS + s0 + t];
    tile[r][t] = (float)((v - stats[c]) * stats[CC + c]);
  }
  __syncthreads();
#pragma unroll
  for (int r0 = 0; r0 < 64; r0 += 4) {
    int r = r0 + rb;
    long long idx = ((long long)(b * SS + s0 + r)) * CC + c0 + t;
    u16 h, l; split2(tile[t][r], h, l);
    xnh[idx] = h; xnl[idx] = l;
  }
}

// ---------------- fp32 [n] -> bf16 hi/lo planes ----------------
__global__ __launch_bounds__(256) void conv_split(const float* __restrict__ src,
                                                  u16* __restrict__ h, u16* __restrict__ l) {
  int i = (blockIdx.x * 256 + threadIdx.x) * 4;
  float4 f = *reinterpret_cast<const float4*>(src + i);
  ushort4 H, L;
  split2(f.x, H.x, L.x); split2(f.y, H.y, L.y); split2(f.z, H.z, L.z); split2(f.w, H.w, L.w);
  *reinterpret_cast<ushort4*>(h + i) = H;
  *reinterpret_cast<ushort4*>(l + i) = L;
}

// ---------------- V fp32 [c][d] -> Vt bf16 [d][c] ----------------
__global__ __launch_bounds__(256) void trans_conv_v(const float* __restrict__ V, u16* __restrict__ Vt) {
  __shared__ float tile[64][65];
  const int c0 = blockIdx.x * 64, d0 = blockIdx.y * 64;
  const int t = threadIdx.x & 63, rb = threadIdx.x >> 6;
#pragma unroll
  for (int r0 = 0; r0 < 64; r0 += 4) {
    int r = r0 + rb;
    tile[r][t] = V[(long long)(c0 + r) * 512 + d0 + t];
  }
  __syncthreads();
#pragma unroll
  for (int r0 = 0; r0 < 64; r0 += 4) {
    int r = r0 + rb;
    Vt[(long long)(d0 + r) * 512 + c0 + t] = f2bf(tile[t][r]);
  }
}

// ---------------- MFMA NT GEMM, 128x128 tile, BK=32, global_load_lds staging ----------------
// (kept for W2t + fallback path)
template <bool ASPLIT, bool BSPLIT, int OUTMODE>
__global__ __launch_bounds__(256) void mfma_nt(
    const u16* __restrict__ Ah, const u16* __restrict__ Al, long long sA,
    const u16* __restrict__ Bh, const u16* __restrict__ Bl, long long sB,
    void* __restrict__ C, void* __restrict__ C2, long long sC,
    int N, int K, float scale, const u16* __restrict__ Rh, const u16* __restrict__ Rl) {
  __shared__ __attribute__((aligned(16))) u16 lah[128 * 32];
  __shared__ __attribute__((aligned(16))) u16 lal[ASPLIT ? 128 * 32 : 8];
  __shared__ __attribute__((aligned(16))) u16 lbh[128 * 32];
  __shared__ __attribute__((aligned(16))) u16 lbl[BSPLIT ? 128 * 32 : 8];

  const int tid = threadIdx.x;
  int bx, by, bz;
  xcd_remap(bx, by, bz);
  const int z = bz;
  const int m0 = by * 128, n0 = bx * 128;
  const int wave = tid >> 6, lane = tid & 63;
  const int wr = (wave >> 1) * 64, wc = (wave & 1) * 64;
  const int lrow = lane & 15, lquad = lane >> 4;
  const long long aB = (long long)z * sA, bB = (long long)z * sB;
  const int srow = tid >> 2, scg = (tid & 3) * 8;
  const int wofs = wave * 512;

  f32x4 acc[4][4];
#pragma unroll
  for (int i = 0; i < 4; i++)
#pragma unroll
    for (int j = 0; j < 4; j++) acc[i][j] = (f32x4){0.f, 0.f, 0.f, 0.f};

  for (int k0 = 0; k0 < K; k0 += 32) {
    const long long ar1 = aB + (long long)(m0 + srow) * K + k0 + scg;
    const long long ar2 = aB + (long long)(m0 + srow + 64) * K + k0 + scg;
    gld16(Ah + ar1, &lah[wofs]);
    gld16(Ah + ar2, &lah[wofs + 2048]);
    if constexpr (ASPLIT) {
      gld16(Al + ar1, &lal[wofs]);
      gld16(Al + ar2, &lal[wofs + 2048]);
    }
    const long long br1 = bB + (long long)(n0 + srow) * K + k0 + scg;
    const long long br2 = bB + (long long)(n0 + srow + 64) * K + k0 + scg;
    gld16(Bh + br1, &lbh[wofs]);
    gld16(Bh + br2, &lbh[wofs + 2048]);
    if constexpr (BSPLIT) {
      gld16(Bl + br1, &lbl[wofs]);
      gld16(Bl + br2, &lbl[wofs + 2048]);
    }
    __syncthreads();

    bf16x8 ah[4], al[ASPLIT ? 4 : 1], bh[4], bl[BSPLIT ? 4 : 1];
#pragma unroll
    for (int i = 0; i < 4; i++) {
      ah[i] = *reinterpret_cast<const bf16x8*>(&lah[(wr + i * 16 + lrow) * 32 + lquad * 8]);
      if constexpr (ASPLIT)
        al[i] = *reinterpret_cast<const bf16x8*>(&lal[(wr + i * 16 + lrow) * 32 + lquad * 8]);
      bh[i] = *reinterpret_cast<const bf16x8*>(&lbh[(wc + i * 16 + lrow) * 32 + lquad * 8]);
      if constexpr (BSPLIT)
        bl[i] = *reinterpret_cast<const bf16x8*>(&lbl[(wc + i * 16 + lrow) * 32 + lquad * 8]);
    }
#pragma unroll
    for (int i = 0; i < 4; i++)
#pragma unroll
      for (int j = 0; j < 4; j++) {
        f32x4 t = acc[i][j];
        if constexpr (ASPLIT) t = __builtin_amdgcn_mfma_f32_16x16x32_bf16(al[i], bh[j], t, 0, 0, 0);
        if constexpr (BSPLIT) t = __builtin_amdgcn_mfma_f32_16x16x32_bf16(ah[i], bl[j], t, 0, 0, 0);
        t = __builtin_amdgcn_mfma_f32_16x16x32_bf16(ah[i], bh[j], t, 0, 0, 0);
        acc[i][j] = t;
      }
    __syncthreads();
  }

  const long long zC = (long long)z * sC;
#pragma unroll
  for (int i = 0; i < 4; i++) {
    int rl_ = wr + i * 16 + lquad * 4;
#pragma unroll
    for (int j = 0; j < 4; j++) {
      int col = n0 + wc + j * 16 + lrow;
#pragma unroll
      for (int r = 0; r < 4; r++) {
        long long idx = zC + (long long)(m0 + rl_ + r) * N + col;
        float val = acc[i][j][r];
        if constexpr (OUTMODE == 0) {
          reinterpret_cast<float*>(C)[idx] = val * scale;
        } else if constexpr (OUTMODE == 1) {
          reinterpret_cast<u16*>(C)[idx] = f2bf(val);
        } else if constexpr (OUTMODE == 2) {
          u16 h, l; split2(val, h, l);
          reinterpret_cast<u16*>(C)[idx] = h;
          reinterpret_cast<u16*>(C2)[idx] = l;
        } else {
          reinterpret_cast<float*>(C)[idx] = val + bf2f(Rh[idx]) + bf2f(Rl[idx]);
        }
      }
    }
  }
}

// ---------------- pipelined MFMA NT GEMM: BM x 256 tile, BK=32, 8 waves, dbuf LDS ----------------
// T2 source-side XOR swizzle, T3 phase schedule, T4 counted vmcnt (never 0 in main loop),
// T5 setprio around MFMA clusters. Staging issued once per K-tile AFTER the final phase
// barrier (buf[cur] provably unread); wait vmcnt(LPT) covers the PREVIOUS tile's loads only.
// Accumulation order identical to mfma_nt (al*bh, ah*bl, ah*bh; k ascending) -> bit-identical.
template <int BM, int APL, int BPL, int OUTMODE, int PHASES, int MW>
__global__ __launch_bounds__(512, MW) void mfma_pipe(
    const u16* __restrict__ Ah, const u16* __restrict__ Al, long long sA,
    const u16* __restrict__ Bh, const u16* __restrict__ Bl, long long sB,
    void* __restrict__ C, void* __restrict__ C2, long long sC,
    int N, int K, float scale, const u16* __restrict__ Rh, const u16* __restrict__ Rl) {
  constexpr int MI = BM / 32;         // i-blocks per wave (wave covers BM/2 rows)
  constexpr int IPP = MI / PHASES;    // i-blocks per phase
  constexpr int LPT = APL * (BM == 256 ? 2 : 1) + BPL * 2;  // gld16 per thread per K-tile
  __shared__ __attribute__((aligned(16))) u16 la[2][APL * BM * 32];
  __shared__ __attribute__((aligned(16))) u16 lb[2][BPL * 256 * 32];

  const int tid = threadIdx.x;
  int bx, by, bz;
  xcd_remap(bx, by, bz);
  const int m0 = by * BM, n0 = bx * 256;
  const int wave = tid >> 6, lane = tid & 63;
  const int wr = (wave >> 2) * (BM / 2), wc = (wave & 3) * 64;  // 2M x 4N waves
  const int lrow = lane & 15, lquad = lane >> 4;
  const long long aB = (long long)bz * sA + (long long)m0 * K;
  const long long bB = (long long)bz * sB + (long long)n0 * K;
  const int srow = tid >> 2;                                    // 0..127
  const int scg = ((tid & 3) ^ ((srow >> 1) & 3)) * 8;          // swizzled source chunk
  const int wofs = wave * 512;                                  // u16: 1 KiB per wave

  f32x4 acc[MI][4];
#pragma unroll
  for (int i = 0; i < MI; i++)
#pragma unroll
    for (int j = 0; j < 4; j++) acc[i][j] = (f32x4){0.f, 0.f, 0.f, 0.f};

  auto stageA = [&](int buf, int k0) {
#pragma unroll
    for (int pl = 0; pl < APL; ++pl) {
      const u16* src = pl ? Al : Ah;
      gld16(src + aB + (long long)srow * K + k0 + scg, &la[buf][pl * BM * 32 + wofs]);
      if constexpr (BM == 256)
        gld16(src + aB + (long long)(srow + 128) * K + k0 + scg, &la[buf][pl * BM * 32 + 4096 + wofs]);
    }
  };
  auto stageB = [&](int buf, int k0) {
#pragma unroll
    for (int pl = 0; pl < BPL; ++pl) {
      const u16* src = pl ? Bl : Bh;
      gld16(src + bB + (long long)srow * K + k0 + scg, &lb[buf][pl * 256 * 32 + wofs]);
      gld16(src + bB + (long long)(srow + 128) * K + k0 + scg, &lb[buf][pl * 256 * 32 + 4096 + wofs]);
    }
  };
  auto rdA = [&](int buf, int pl, int row) -> bf16x8 {
    return *reinterpret_cast<const bf16x8*>(
        &la[buf][pl * BM * 32 + row * 32 + (lquad ^ ((row >> 1) & 3)) * 8]);
  };
  auto rdB = [&](int buf, int pl, int row) -> bf16x8 {
    return *reinterpret_cast<const bf16x8*>(
        &lb[buf][pl * 256 * 32 + row * 32 + (lquad ^ ((row >> 1) & 3)) * 8]);
  };

  const int nkt = K >> 5;

  // prologue: stage K-tiles 0 and 1; wait only for tile 0 (counted)
  stageA(0, 0);
  stageB(0, 0);
  if (nkt > 1) {
    stageA(1, 32);
    stageB(1, 32);
    wait_vmcnt<LPT>();
  } else {
    wait_vmcnt<0>();
  }
  __builtin_amdgcn_s_barrier();

  bf16x8 bh_[4], bl_[BPL == 2 ? 4 : 1];

  for (int kt = 0; kt < nkt; ++kt) {
    const int cur = kt & 1;

#pragma unroll
    for (int p = 0; p < PHASES; ++p) {
      bf16x8 a_h[IPP], a_l[IPP];
#pragma unroll
      for (int ii = 0; ii < IPP; ++ii) {
        int row = wr + (p * IPP + ii) * 16 + lrow;
        a_h[ii] = rdA(cur, 0, row);
        if constexpr (APL == 2) a_l[ii] = rdA(cur, 1, row);
      }
      if (p == 0) {
#pragma unroll
        for (int j = 0; j < 4; ++j) {
          int row = wc + j * 16 + lrow;
          bh_[j] = rdB(cur, 0, row);
          if constexpr (BPL == 2) bl_[j] = rdB(cur, 1, row);
        }
      }
      __builtin_amdgcn_sched_barrier(0);
      __builtin_amdgcn_s_barrier();
      asm volatile("s_waitcnt lgkmcnt(0)" ::: "memory");
      __builtin_amdgcn_sched_barrier(0);
      __builtin_amdgcn_s_setprio(1);
#pragma unroll
      for (int ii = 0; ii < IPP; ++ii) {
        int i = p * IPP + ii;
#pragma unroll
        for (int j = 0; j < 4; ++j) {
          f32x4 t = acc[i][j];
          if constexpr (APL == 2) t = __builtin_amdgcn_mfma_f32_16x16x32_bf16(a_l[ii], bh_[j], t, 0, 0, 0);
          if constexpr (BPL == 2) t = __builtin_amdgcn_mfma_f32_16x16x32_bf16(a_h[ii], bl_[j], t, 0, 0, 0);
          t = __builtin_amdgcn_mfma_f32_16x16x32_bf16(a_h[ii], bh_[j], t, 0, 0, 0);
          acc[i][j] = t;
        }
      }
      __builtin_amdgcn_s_setprio(0);
      __builtin_amdgcn_s_barrier();
    }

    // tile end: all waves are past their reads of buf[cur] (phase barriers above).
    if (kt + 2 < nkt) {
      const int nk2 = (kt + 2) << 5;
      stageA(cur, nk2);
      stageB(cur, nk2);
      wait_vmcnt<LPT>();   // waits for tile kt+1's loads; kt+2's stay in flight
      __builtin_amdgcn_s_barrier();
    } else if (kt + 1 < nkt) {
      wait_vmcnt<0>();     // epilogue drain for the final tile
      __builtin_amdgcn_s_barrier();
    }
  }

  const long long zC = (long long)bz * sC;
#pragma unroll
  for (int i = 0; i < MI; i++) {
    int rl_ = wr + i * 16 + lquad * 4;
#pragma unroll
    for (int j = 0; j < 4; j++) {
      int col = n0 + wc + j * 16 + lrow;
#pragma unroll
      for (int r = 0; r < 4; r++) {
        long long idx = zC + (long long)(m0 + rl_ + r) * N + col;
        float val = acc[i][j][r];
        if constexpr (OUTMODE == 0) {
          reinterpret_cast<float*>(C)[idx] = val * scale;
        } else if constexpr (OUTMODE == 1) {
          reinterpret_cast<u16*>(C)[idx] = f2bf(val);
        } else if constexpr (OUTMODE == 2) {
          u16 h, l; split2(val, h, l);
          reinterpret_cast<u16*>(C)[idx] = h;
          reinterpret_cast<u16*>(C2)[idx] = l;
        } else {
          reinterpret_cast<float*>(C)[idx] = val + bf2f(Rh[idx]) + bf2f(Rl[idx]);
        }
      }
    }
  }
}

// ---------------- softmax over batch axis: scomp fp32 -> attw bf16 (scalar, fallback) ----------------
__global__ __launch_bounds__(256) void softmax_chunk(const float* __restrict__ sc,
                                                     u16* __restrict__ w, long long plane) {
  long long idx = (long long)blockIdx.x * 256 + threadIdx.x;
  float v[16];
  float m = -3.4e38f;
#pragma unroll
  for (int b = 0; b < 16; b++) { v[b] = sc[(long long)b * plane + idx]; m = fmaxf(m, v[b]); }
  float s = 0.f;
#pragma unroll
  for (int b = 0; b < 16; b++) { v[b] = expf(v[b] - m); s += v[b]; }
  float inv = 1.f / s;
#pragma unroll
  for (int b = 0; b < 16; b++) w[(long long)b * plane + idx] = f2bf(v[b] * inv);
}

// ---------------- softmax over batch axis, float4-vectorized ----------------
__global__ __launch_bounds__(256) void softmax_chunk4(const float* __restrict__ sc,
                                                      u16* __restrict__ w, long long plane) {
  long long idx = ((long long)blockIdx.x * 256 + threadIdx.x) * 4;
  float4 v[16];
  float4 m = make_float4(-3.4e38f, -3.4e38f, -3.4e38f, -3.4e38f);
#pragma unroll
  for (int b = 0; b < 16; b++) {
    v[b] = *reinterpret_cast<const float4*>(sc + (long long)b * plane + idx);
    m.x = fmaxf(m.x, v[b].x); m.y = fmaxf(m.y, v[b].y);
    m.z = fmaxf(m.z, v[b].z); m.w = fmaxf(m.w, v[b].w);
  }
  float4 s = make_float4(0.f, 0.f, 0.f, 0.f);
#pragma unroll
  for (int b = 0; b < 16; b++) {
    v[b].x = expf(v[b].x - m.x); s.x += v[b].x;
    v[b].y = expf(v[b].y - m.y); s.y += v[b].y;
    v[b].z = expf(v[b].z - m.z); s.z += v[b].z;
    v[b].w = expf(v[b].w - m.w); s.w += v[b].w;
  }
  float4 inv = make_float4(1.f / s.x, 1.f / s.y, 1.f / s.z, 1.f / s.w);
#pragma unroll
  for (int b = 0; b < 16; b++) {
    ushort4 o;
    o.x = f2bf(v[b].x * inv.x); o.y = f2bf(v[b].y * inv.y);
    o.z = f2bf(v[b].z * inv.z); o.w = f2bf(v[b].w * inv.w);
    *reinterpret_cast<ushort4*>(w + (long long)b * plane + idx) = o;
  }
}

extern "C" void kernel_launch(void* const* d_in, const int* in_sizes, int n_in,
                              void* d_out, int out_size, void* d_ws, size_t ws_size,
                              hipStream_t stream) {
  (void)in_sizes; (void)n_in; (void)out_size;
  const float* x  = (const float*)d_in[0];
  const float* Qw = (const float*)d_in[1];
  const float* Kw = (const float*)d_in[2];
  const float* Vw = (const float*)d_in[3];
  float* out = (float*)d_out;
  char* ws = (char*)d_ws;

  const float scale = 0.04419417382415922f;  // 1/sqrt(512)

  // ---- big layout (unchunked): needs 188,235,776 B ----
  if (ws_size >= 188235776ULL) {
    double* stats = (double*)(ws + 256);
    u16* xnh  = (u16*)(ws + 16384);
    u16* xnl  = (u16*)(ws + 16793600);
    u16* Vt   = (u16*)(ws + 33570816);
    u16* W2th = (u16*)(ws + 34095104);
    u16* W2tl = (u16*)(ws + 34619392);
    u16* Qh   = (u16*)(ws + 35143680);
    u16* Ql   = (u16*)(ws + 35667968);
    u16* Kh   = (u16*)(ws + 36192256);
    u16* Kl   = (u16*)(ws + 36716544);
    u16* vt   = (u16*)(ws + 37240832);   // [16,512,1024] bf16  16 MB
    u16* th   = (u16*)(ws + 54018048);   // [16,1024,512] hi    16 MB
    u16* tl   = (u16*)(ws + 70795264);   // lo                  16 MB
    float* scomp = (float*)(ws + 87572480);   // [16,1024,1024] fp32  64 MB
    u16* attw = (u16*)(ws + 154681344);  // [16,1024,1024] bf16  32 MB

    bn_stats_f64<<<CC, 256, 0, stream>>>(x, stats);
    bn_apply_split<<<dim3(16, 8, 16), 256, 0, stream>>>(x, stats, xnh, xnl);
    conv_split<<<256, 256, 0, stream>>>(Qw, Qh, Ql);
    conv_split<<<256, 256, 0, stream>>>(Kw, Kh, Kl);
    trans_conv_v<<<dim3(8, 8), 256, 0, stream>>>(Vw, Vt);

    // W2t[c'][c] = sum_d K[c',d] Q[c,d]   (small; 128^2 kernel)
    mfma_nt<true, true, 2><<<dim3(4, 4, 1), 256, 0, stream>>>(
        Kh, Kl, 0, Qh, Ql, 0, W2th, W2tl, 0, 512, 512, 1.0f, nullptr, nullptr);

    // vt[b][d][token] = sum_c Vt[d,c] * xn[b,token,c]   128x256 tiles, 256 blocks
    mfma_pipe<128, 1, 2, 1, 2, 4><<<dim3(4, 4, 16), 512, 0, stream>>>(
        Vt, nullptr, 0, xnh, xnl, 524288, vt, nullptr, 524288, 1024, 512, 1.0f, nullptr, nullptr);

    // t[b,s,c'] = sum_c xn[b,s,c] * W2t[c'][c]   128x256 tiles, 256 blocks
    mfma_pipe<128, 2, 2, 2, 2, 2><<<dim3(2, 8, 16), 512, 0, stream>>>(
        xnh, xnl, 524288, W2th, W2tl, 0, th, tl, 524288, 512, 512, 1.0f, nullptr, nullptr);

    // scores[b,s,j] = scale * sum_c' t[b,s,c'] * xn[b,j,c']   256x256 tiles, 256 blocks
    mfma_pipe<256, 2, 2, 0, 4, 2><<<dim3(4, 4, 16), 512, 0, stream>>>(
        th, tl, 524288, xnh, xnl, 524288, scomp, nullptr, 1048576, 1024, 512, scale, nullptr, nullptr);

    softmax_chunk4<<<1024, 256, 0, stream>>>(scomp, attw, 1048576LL);

    // out[b,s,d] = sum_k attw[b,s,k] * vt[b,d,k] + xn residual   128x256 tiles, 256 blocks
    mfma_pipe<128, 1, 1, 3, 1, 4><<<dim3(2, 8, 16), 512, 0, stream>>>(
        attw, nullptr, 1048576, vt, nullptr, 524288,
        out, nullptr, 524288, 512, 1024, 1.0f, xnh, xnl);
    return;
  }

  // ---- fallback: proven chunked layout (85,475,328 B) ----
  double* stats = (double*)(ws + 256);
  u16* xnh  = (u16*)(ws + 16384);
  u16* xnl  = (u16*)(ws + 16793600);
  u16* Vt   = (u16*)(ws + 33570816);
  u16* W2th = (u16*)(ws + 34095104);
  u16* W2tl = (u16*)(ws + 34619392);
  u16* vt   = (u16*)(ws + 35143680);
  u16* th   = (u16*)(ws + 51920896);
  u16* tl   = (u16*)(ws + 56115200);
  float* scomp = (float*)(ws + 60309504);
  u16* attw = (u16*)(ws + 77086720);
  u16* Qh = (u16*)(ws + 51920896);
  u16* Ql = (u16*)(ws + 52445184);
  u16* Kh = (u16*)(ws + 52969472);
  u16* Kl = (u16*)(ws + 53493760);

  bn_stats_f64<<<CC, 256, 0, stream>>>(x, stats);
  bn_apply_split<<<dim3(16, 8, 16), 256, 0, stream>>>(x, stats, xnh, xnl);
  conv_split<<<256, 256, 0, stream>>>(Qw, Qh, Ql);
  conv_split<<<256, 256, 0, stream>>>(Kw, Kh, Kl);
  trans_conv_v<<<dim3(8, 8), 256, 0, stream>>>(Vw, Vt);

  mfma_nt<true, true, 2><<<dim3(4, 4, 1), 256, 0, stream>>>(
      Kh, Kl, 0, Qh, Ql, 0, W2th, W2tl, 0, 512, 512, 1.0f, nullptr, nullptr);

  mfma_nt<false, true, 1><<<dim3(8, 4, 16), 256, 0, stream>>>(
      Vt, nullptr, 0, xnh, xnl, 524288, vt, nullptr, 524288, 1024, 512, 1.0f, nullptr, nullptr);

  for (int ci = 0; ci < 4; ci++) {
    int s0c = ci * R;
    mfma_nt<true, true, 2><<<dim3(4, 2, 16), 256, 0, stream>>>(
        xnh + (long long)s0c * 512, xnl + (long long)s0c * 512, 524288,
        W2th, W2tl, 0, th, tl, 131072, 512, 512, 1.0f, nullptr, nullptr);
    mfma_nt<true, true, 0><<<dim3(8, 2, 16), 256, 0, stream>>>(
        th, tl, 131072, xnh, xnl, 524288, scomp, nullptr, 262144,
        1024, 512, scale, nullptr, nullptr);
    softmax_chunk<<<1024, 256, 0, stream>>>(scomp, attw, 262144LL);
    mfma_nt<false, false, 3><<<dim3(4, 2, 16), 256, 0, stream>>>(
        attw, nullptr, 262144, vt, nullptr, 524288,
        out + (long long)s0c * 512, nullptr, 524288, 512, 1024, 1.0f,
        xnh + (long long)s0c * 512, xnl + (long long)s0c * 512);
  }
}

// Round 5
// 315.266 us; speedup vs baseline: 1.0676x; 1.0676x over previous
//
#include <hip/hip_runtime.h>

typedef unsigned short u16;
typedef __bf16 bf16x8 __attribute__((ext_vector_type(8)));
typedef float f32x4 __attribute__((ext_vector_type(4)));

static constexpr int BB = 16;    // batch
static constexpr int CC = 512;   // channels
static constexpr int SS = 1024;  // seq
static constexpr int R  = 256;   // q-chunk rows (small-ws fallback path)

__device__ __forceinline__ u16 f2bf(float f) {
  __bf16 h = (__bf16)f; return __builtin_bit_cast(unsigned short, h);
}
__device__ __forceinline__ float bf2f(u16 u) {
  union { unsigned int i; float f; } v; v.i = ((unsigned int)u) << 16; return v.f;
}
__device__ __forceinline__ void split2(float v, u16& hi, u16& lo) {
  __bf16 h = (__bf16)v;
  float hf = (float)h;
  __bf16 l = (__bf16)(v - hf);
  hi = __builtin_bit_cast(unsigned short, h);
  lo = __builtin_bit_cast(unsigned short, l);
}

// async global->LDS, 16B per lane; LDS dest = wave-uniform base + lane*16
__device__ __forceinline__ void gld16(const u16* g, u16* l) {
  __builtin_amdgcn_global_load_lds(
      (const __attribute__((address_space(1))) void*)g,
      (__attribute__((address_space(3))) void*)l, 16, 0, 0);
}

// counted vmcnt wait with compile-time literal (T4)
template <int N>
__device__ __forceinline__ void wait_vmcnt() {
  if constexpr (N == 0) asm volatile("s_waitcnt vmcnt(0)" ::: "memory");
  else if constexpr (N == 1) asm volatile("s_waitcnt vmcnt(1)" ::: "memory");
  else if constexpr (N == 2) asm volatile("s_waitcnt vmcnt(2)" ::: "memory");
  else if constexpr (N == 3) asm volatile("s_waitcnt vmcnt(3)" ::: "memory");
  else if constexpr (N == 4) asm volatile("s_waitcnt vmcnt(4)" ::: "memory");
  else if constexpr (N == 5) asm volatile("s_waitcnt vmcnt(5)" ::: "memory");
  else if constexpr (N == 6) asm volatile("s_waitcnt vmcnt(6)" ::: "memory");
  else if constexpr (N == 7) asm volatile("s_waitcnt vmcnt(7)" ::: "memory");
  else if constexpr (N == 8) asm volatile("s_waitcnt vmcnt(8)" ::: "memory");
  else if constexpr (N == 9) asm volatile("s_waitcnt vmcnt(9)" ::: "memory");
  else if constexpr (N == 10) asm volatile("s_waitcnt vmcnt(10)" ::: "memory");
  else if constexpr (N == 11) asm volatile("s_waitcnt vmcnt(11)" ::: "memory");
  else asm volatile("s_waitcnt vmcnt(12)" ::: "memory");
}

// bijective XCD-chunked remap of a 3D grid (requires nwg % 8 == 0; all our grids satisfy)
__device__ __forceinline__ void xcd_remap(int& bx, int& by, int& bz) {
  int gx = gridDim.x, gy = gridDim.y;
  int nwg = gx * gy * gridDim.z;
  int flat = (blockIdx.z * gy + blockIdx.y) * gx + blockIdx.x;
  int swz = ((nwg & 7) == 0) ? (flat & 7) * (nwg >> 3) + (flat >> 3) : flat;
  bx = swz % gx;
  int t1 = swz / gx;
  by = t1 % gy;
  bz = t1 / gy;
}

// ---------------- BatchNorm stats per channel over (B,S), fp64 ----------------
__global__ __launch_bounds__(256) void bn_stats_f64(const float* __restrict__ x, double* __restrict__ stats) {
  const int c = blockIdx.x;
  double s = 0.0, s2 = 0.0;
  for (int n = threadIdx.x; n < BB * SS; n += 256) {
    int b = n >> 10, sp = n & (SS - 1);
    double v = (double)x[((long long)(b * CC + c)) * SS + sp];
    s += v; s2 += v * v;
  }
  __shared__ double sh[256], sh2[256];
  sh[threadIdx.x] = s; sh2[threadIdx.x] = s2;
  __syncthreads();
  for (int off = 128; off > 0; off >>= 1) {
    if (threadIdx.x < off) { sh[threadIdx.x] += sh[threadIdx.x + off]; sh2[threadIdx.x] += sh2[threadIdx.x + off]; }
    __syncthreads();
  }
  if (threadIdx.x == 0) {
    double mean = sh[0] / 16384.0;
    double var = sh2[0] / 16384.0 - mean * mean;   // biased (torch BN)
    stats[c] = mean;
    stats[CC + c] = 1.0 / sqrt(var + 1e-5);
  }
}

// ---------------- normalize + transpose + split: x [b,c,s] -> xnh/xnl bf16 [b*S + s][c] ----------------
__global__ __launch_bounds__(256) void bn_apply_split(const float* __restrict__ x,
                                                      const double* __restrict__ stats,
                                                      u16* __restrict__ xnh, u16* __restrict__ xnl) {
  __shared__ float tile[64][65];
  const int b = blockIdx.z;
  const int s0 = blockIdx.x * 64, c0 = blockIdx.y * 64;
  const int t = threadIdx.x & 63, rb = threadIdx.x >> 6;
#pragma unroll
  for (int r0 = 0; r0 < 64; r0 += 4) {
    int r = r0 + rb;
    int c = c0 + r;
    double v = (double)x[((long long)(b * CC + c)) * SS + s0 + t];
    tile[r][t] = (float)((v - stats[c]) * stats[CC + c]);
  }
  __syncthreads();
#pragma unroll
  for (int r0 = 0; r0 < 64; r0 += 4) {
    int r = r0 + rb;
    long long idx = ((long long)(b * SS + s0 + r)) * CC + c0 + t;
    u16 h, l; split2(tile[t][r], h, l);
    xnh[idx] = h; xnl[idx] = l;
  }
}

// ---------------- fp32 [n] -> bf16 hi/lo planes ----------------
__global__ __launch_bounds__(256) void conv_split(const float* __restrict__ src,
                                                  u16* __restrict__ h, u16* __restrict__ l) {
  int i = (blockIdx.x * 256 + threadIdx.x) * 4;
  float4 f = *reinterpret_cast<const float4*>(src + i);
  ushort4 H, L;
  split2(f.x, H.x, L.x); split2(f.y, H.y, L.y); split2(f.z, H.z, L.z); split2(f.w, H.w, L.w);
  *reinterpret_cast<ushort4*>(h + i) = H;
  *reinterpret_cast<ushort4*>(l + i) = L;
}

// ---------------- V fp32 [c][d] -> Vt bf16 [d][c] ----------------
__global__ __launch_bounds__(256) void trans_conv_v(const float* __restrict__ V, u16* __restrict__ Vt) {
  __shared__ float tile[64][65];
  const int c0 = blockIdx.x * 64, d0 = blockIdx.y * 64;
  const int t = threadIdx.x & 63, rb = threadIdx.x >> 6;
#pragma unroll
  for (int r0 = 0; r0 < 64; r0 += 4) {
    int r = r0 + rb;
    tile[r][t] = V[(long long)(c0 + r) * 512 + d0 + t];
  }
  __syncthreads();
#pragma unroll
  for (int r0 = 0; r0 < 64; r0 += 4) {
    int r = r0 + rb;
    Vt[(long long)(d0 + r) * 512 + c0 + t] = f2bf(tile[t][r]);
  }
}

// ---------------- MFMA NT GEMM, 128x128 tile, BK=32, global_load_lds staging ----------------
// (kept for W2t + fallback path)
template <bool ASPLIT, bool BSPLIT, int OUTMODE>
__global__ __launch_bounds__(256) void mfma_nt(
    const u16* __restrict__ Ah, const u16* __restrict__ Al, long long sA,
    const u16* __restrict__ Bh, const u16* __restrict__ Bl, long long sB,
    void* __restrict__ C, void* __restrict__ C2, long long sC,
    int N, int K, float scale, const u16* __restrict__ Rh, const u16* __restrict__ Rl) {
  __shared__ __attribute__((aligned(16))) u16 lah[128 * 32];
  __shared__ __attribute__((aligned(16))) u16 lal[ASPLIT ? 128 * 32 : 8];
  __shared__ __attribute__((aligned(16))) u16 lbh[128 * 32];
  __shared__ __attribute__((aligned(16))) u16 lbl[BSPLIT ? 128 * 32 : 8];

  const int tid = threadIdx.x;
  int bx, by, bz;
  xcd_remap(bx, by, bz);
  const int z = bz;
  const int m0 = by * 128, n0 = bx * 128;
  const int wave = tid >> 6, lane = tid & 63;
  const int wr = (wave >> 1) * 64, wc = (wave & 1) * 64;
  const int lrow = lane & 15, lquad = lane >> 4;
  const long long aB = (long long)z * sA, bB = (long long)z * sB;
  const int srow = tid >> 2, scg = (tid & 3) * 8;
  const int wofs = wave * 512;

  f32x4 acc[4][4];
#pragma unroll
  for (int i = 0; i < 4; i++)
#pragma unroll
    for (int j = 0; j < 4; j++) acc[i][j] = (f32x4){0.f, 0.f, 0.f, 0.f};

  for (int k0 = 0; k0 < K; k0 += 32) {
    const long long ar1 = aB + (long long)(m0 + srow) * K + k0 + scg;
    const long long ar2 = aB + (long long)(m0 + srow + 64) * K + k0 + scg;
    gld16(Ah + ar1, &lah[wofs]);
    gld16(Ah + ar2, &lah[wofs + 2048]);
    if constexpr (ASPLIT) {
      gld16(Al + ar1, &lal[wofs]);
      gld16(Al + ar2, &lal[wofs + 2048]);
    }
    const long long br1 = bB + (long long)(n0 + srow) * K + k0 + scg;
    const long long br2 = bB + (long long)(n0 + srow + 64) * K + k0 + scg;
    gld16(Bh + br1, &lbh[wofs]);
    gld16(Bh + br2, &lbh[wofs + 2048]);
    if constexpr (BSPLIT) {
      gld16(Bl + br1, &lbl[wofs]);
      gld16(Bl + br2, &lbl[wofs + 2048]);
    }
    __syncthreads();

    bf16x8 ah[4], al[ASPLIT ? 4 : 1], bh[4], bl[BSPLIT ? 4 : 1];
#pragma unroll
    for (int i = 0; i < 4; i++) {
      ah[i] = *reinterpret_cast<const bf16x8*>(&lah[(wr + i * 16 + lrow) * 32 + lquad * 8]);
      if constexpr (ASPLIT)
        al[i] = *reinterpret_cast<const bf16x8*>(&lal[(wr + i * 16 + lrow) * 32 + lquad * 8]);
      bh[i] = *reinterpret_cast<const bf16x8*>(&lbh[(wc + i * 16 + lrow) * 32 + lquad * 8]);
      if constexpr (BSPLIT)
        bl[i] = *reinterpret_cast<const bf16x8*>(&lbl[(wc + i * 16 + lrow) * 32 + lquad * 8]);
    }
#pragma unroll
    for (int i = 0; i < 4; i++)
#pragma unroll
      for (int j = 0; j < 4; j++) {
        f32x4 t = acc[i][j];
        if constexpr (ASPLIT) t = __builtin_amdgcn_mfma_f32_16x16x32_bf16(al[i], bh[j], t, 0, 0, 0);
        if constexpr (BSPLIT) t = __builtin_amdgcn_mfma_f32_16x16x32_bf16(ah[i], bl[j], t, 0, 0, 0);
        t = __builtin_amdgcn_mfma_f32_16x16x32_bf16(ah[i], bh[j], t, 0, 0, 0);
        acc[i][j] = t;
      }
    __syncthreads();
  }

  const long long zC = (long long)z * sC;
#pragma unroll
  for (int i = 0; i < 4; i++) {
    int rl_ = wr + i * 16 + lquad * 4;
#pragma unroll
    for (int j = 0; j < 4; j++) {
      int col = n0 + wc + j * 16 + lrow;
#pragma unroll
      for (int r = 0; r < 4; r++) {
        long long idx = zC + (long long)(m0 + rl_ + r) * N + col;
        float val = acc[i][j][r];
        if constexpr (OUTMODE == 0) {
          reinterpret_cast<float*>(C)[idx] = val * scale;
        } else if constexpr (OUTMODE == 1) {
          reinterpret_cast<u16*>(C)[idx] = f2bf(val);
        } else if constexpr (OUTMODE == 2) {
          u16 h, l; split2(val, h, l);
          reinterpret_cast<u16*>(C)[idx] = h;
          reinterpret_cast<u16*>(C2)[idx] = l;
        } else {
          reinterpret_cast<float*>(C)[idx] = val + bf2f(Rh[idx]) + bf2f(Rl[idx]);
        }
      }
    }
  }
}

// ---------------- pipelined MFMA NT GEMM: 128 x 256 tile, BK=32, 8 waves, ----------------
// TRIPLE-buffered LDS (2-ahead prefetch) so the end-of-tile vmcnt is truly counted:
// tile kt+2's loads (issued in kt's phases 0/1, interleaved with MFMA) stay in flight,
// tile kt+1's loads are a full K-tile old when waited on. Per-phase structure identical
// to the proven R3 schedule (T2 src-swizzle, barriers, lgkmcnt(0), setprio).
// Accumulation order identical to mfma_nt (al*bh, ah*bl, ah*bh; k ascending) -> bit-identical.
template <int APL, int BPL, int OUTMODE, int PHASES, int MW>
__global__ __launch_bounds__(512, MW) void mfma_pipe3(
    const u16* __restrict__ Ah, const u16* __restrict__ Al, long long sA,
    const u16* __restrict__ Bh, const u16* __restrict__ Bl, long long sB,
    void* __restrict__ C, void* __restrict__ C2, long long sC,
    int N, int K, float scale, const u16* __restrict__ Rh, const u16* __restrict__ Rl) {
  constexpr int BM = 128;
  constexpr int MI = BM / 32;         // 4 i-blocks per wave (wave covers 64 rows)
  constexpr int IPP = MI / PHASES;    // i-blocks per phase
  constexpr int LPT = APL + BPL * 2;  // gld16 per thread per K-tile
  __shared__ __attribute__((aligned(16))) u16 la[3][APL * BM * 32];
  __shared__ __attribute__((aligned(16))) u16 lb[3][BPL * 256 * 32];

  const int tid = threadIdx.x;
  int bx, by, bz;
  xcd_remap(bx, by, bz);
  const int m0 = by * BM, n0 = bx * 256;
  const int wave = tid >> 6, lane = tid & 63;
  const int wr = (wave >> 2) * (BM / 2), wc = (wave & 3) * 64;  // 2M x 4N waves
  const int lrow = lane & 15, lquad = lane >> 4;
  const long long aB = (long long)bz * sA + (long long)m0 * K;
  const long long bB = (long long)bz * sB + (long long)n0 * K;
  const int srow = tid >> 2;                                    // 0..127
  const int scg = ((tid & 3) ^ ((srow >> 1) & 3)) * 8;          // swizzled source chunk
  const int wofs = wave * 512;                                  // u16: 1 KiB per wave

  f32x4 acc[MI][4];
#pragma unroll
  for (int i = 0; i < MI; i++)
#pragma unroll
    for (int j = 0; j < 4; j++) acc[i][j] = (f32x4){0.f, 0.f, 0.f, 0.f};

  auto stageA = [&](int buf, int k0) {
#pragma unroll
    for (int pl = 0; pl < APL; ++pl) {
      const u16* src = pl ? Al : Ah;
      gld16(src + aB + (long long)srow * K + k0 + scg, &la[buf][pl * BM * 32 + wofs]);
    }
  };
  auto stageB = [&](int buf, int k0) {
#pragma unroll
    for (int pl = 0; pl < BPL; ++pl) {
      const u16* src = pl ? Bl : Bh;
      gld16(src + bB + (long long)srow * K + k0 + scg, &lb[buf][pl * 256 * 32 + wofs]);
      gld16(src + bB + (long long)(srow + 128) * K + k0 + scg, &lb[buf][pl * 256 * 32 + 4096 + wofs]);
    }
  };
  auto rdA = [&](int buf, int pl, int row) -> bf16x8 {
    return *reinterpret_cast<const bf16x8*>(
        &la[buf][pl * BM * 32 + row * 32 + (lquad ^ ((row >> 1) & 3)) * 8]);
  };
  auto rdB = [&](int buf, int pl, int row) -> bf16x8 {
    return *reinterpret_cast<const bf16x8*>(
        &lb[buf][pl * 256 * 32 + row * 32 + (lquad ^ ((row >> 1) & 3)) * 8]);
  };

  const int nkt = K >> 5;

  // prologue: stage K-tiles 0 and 1 into bufs 0,1; wait only for tile 0 (tile 1 stays in flight)
  stageA(0, 0);
  stageB(0, 0);
  if (nkt > 1) {
    stageA(1, 32);
    stageB(1, 32);
    wait_vmcnt<LPT>();
  } else {
    wait_vmcnt<0>();
  }
  __builtin_amdgcn_s_barrier();

  bf16x8 bh_[4], bl_[BPL == 2 ? 4 : 1];
  int cur = 0;

  for (int kt = 0; kt < nkt; ++kt) {
    int b2 = cur + 2; if (b2 >= 3) b2 -= 3;     // buffer for tile kt+2
    const int nk2 = (kt + 2) << 5;
    const bool pf = (kt + 2) < nkt;

#pragma unroll
    for (int p = 0; p < PHASES; ++p) {
      bf16x8 a_h[IPP], a_l[IPP];
#pragma unroll
      for (int ii = 0; ii < IPP; ++ii) {
        int row = wr + (p * IPP + ii) * 16 + lrow;
        a_h[ii] = rdA(cur, 0, row);
        if constexpr (APL == 2) a_l[ii] = rdA(cur, 1, row);
      }
      if (p == 0) {
#pragma unroll
        for (int j = 0; j < 4; ++j) {
          int row = wc + j * 16 + lrow;
          bh_[j] = rdB(cur, 0, row);
          if constexpr (BPL == 2) bl_[j] = rdB(cur, 1, row);
        }
      }
      // prefetch tile kt+2 (2 ahead), interleaved with compute phases
      if (pf) {
        if constexpr (PHASES == 1) {
          stageA(b2, nk2);
          stageB(b2, nk2);
        } else {
          if (p == 0) stageA(b2, nk2);
          else if (p == 1) stageB(b2, nk2);
        }
      }
      __builtin_amdgcn_sched_barrier(0);
      __builtin_amdgcn_s_barrier();
      asm volatile("s_waitcnt lgkmcnt(0)" ::: "memory");
      __builtin_amdgcn_sched_barrier(0);
      __builtin_amdgcn_s_setprio(1);
#pragma unroll
      for (int ii = 0; ii < IPP; ++ii) {
        int i = p * IPP + ii;
#pragma unroll
        for (int j = 0; j < 4; ++j) {
          f32x4 t = acc[i][j];
          if constexpr (APL == 2) t = __builtin_amdgcn_mfma_f32_16x16x32_bf16(a_l[ii], bh_[j], t, 0, 0, 0);
          if constexpr (BPL == 2) t = __builtin_amdgcn_mfma_f32_16x16x32_bf16(a_h[ii], bl_[j], t, 0, 0, 0);
          t = __builtin_amdgcn_mfma_f32_16x16x32_bf16(a_h[ii], bh_[j], t, 0, 0, 0);
          acc[i][j] = t;
        }
      }
      __builtin_amdgcn_s_setprio(0);
      if (p == PHASES - 1) {
        // counted boundary wait: tile kt+1's loads are a full K-tile old; tile kt+2's
        // LPT loads stay in flight. Only the last two boundaries drain.
        if (pf) wait_vmcnt<LPT>();
        else if (kt + 1 < nkt) wait_vmcnt<0>();
      }
      __builtin_amdgcn_s_barrier();
    }
    cur = (cur + 1 == 3) ? 0 : cur + 1;
  }

  const long long zC = (long long)bz * sC;
#pragma unroll
  for (int i = 0; i < MI; i++) {
    int rl_ = wr + i * 16 + lquad * 4;
#pragma unroll
    for (int j = 0; j < 4; j++) {
      int col = n0 + wc + j * 16 + lrow;
#pragma unroll
      for (int r = 0; r < 4; r++) {
        long long idx = zC + (long long)(m0 + rl_ + r) * N + col;
        float val = acc[i][j][r];
        if constexpr (OUTMODE == 0) {
          reinterpret_cast<float*>(C)[idx] = val * scale;
        } else if constexpr (OUTMODE == 1) {
          reinterpret_cast<u16*>(C)[idx] = f2bf(val);
        } else if constexpr (OUTMODE == 2) {
          u16 h, l; split2(val, h, l);
          reinterpret_cast<u16*>(C)[idx] = h;
          reinterpret_cast<u16*>(C2)[idx] = l;
        } else {
          reinterpret_cast<float*>(C)[idx] = val + bf2f(Rh[idx]) + bf2f(Rl[idx]);
        }
      }
    }
  }
}

// ---------------- softmax over batch axis: scomp fp32 -> attw bf16 (scalar, fallback) ----------------
__global__ __launch_bounds__(256) void softmax_chunk(const float* __restrict__ sc,
                                                     u16* __restrict__ w, long long plane) {
  long long idx = (long long)blockIdx.x * 256 + threadIdx.x;
  float v[16];
  float m = -3.4e38f;
#pragma unroll
  for (int b = 0; b < 16; b++) { v[b] = sc[(long long)b * plane + idx]; m = fmaxf(m, v[b]); }
  float s = 0.f;
#pragma unroll
  for (int b = 0; b < 16; b++) { v[b] = expf(v[b] - m); s += v[b]; }
  float inv = 1.f / s;
#pragma unroll
  for (int b = 0; b < 16; b++) w[(long long)b * plane + idx] = f2bf(v[b] * inv);
}

// ---------------- softmax over batch axis, float4-vectorized ----------------
__global__ __launch_bounds__(256) void softmax_chunk4(const float* __restrict__ sc,
                                                      u16* __restrict__ w, long long plane) {
  long long idx = ((long long)blockIdx.x * 256 + threadIdx.x) * 4;
  float4 v[16];
  float4 m = make_float4(-3.4e38f, -3.4e38f, -3.4e38f, -3.4e38f);
#pragma unroll
  for (int b = 0; b < 16; b++) {
    v[b] = *reinterpret_cast<const float4*>(sc + (long long)b * plane + idx);
    m.x = fmaxf(m.x, v[b].x); m.y = fmaxf(m.y, v[b].y);
    m.z = fmaxf(m.z, v[b].z); m.w = fmaxf(m.w, v[b].w);
  }
  float4 s = make_float4(0.f, 0.f, 0.f, 0.f);
#pragma unroll
  for (int b = 0; b < 16; b++) {
    v[b].x = expf(v[b].x - m.x); s.x += v[b].x;
    v[b].y = expf(v[b].y - m.y); s.y += v[b].y;
    v[b].z = expf(v[b].z - m.z); s.z += v[b].z;
    v[b].w = expf(v[b].w - m.w); s.w += v[b].w;
  }
  float4 inv = make_float4(1.f / s.x, 1.f / s.y, 1.f / s.z, 1.f / s.w);
#pragma unroll
  for (int b = 0; b < 16; b++) {
    ushort4 o;
    o.x = f2bf(v[b].x * inv.x); o.y = f2bf(v[b].y * inv.y);
    o.z = f2bf(v[b].z * inv.z); o.w = f2bf(v[b].w * inv.w);
    *reinterpret_cast<ushort4*>(w + (long long)b * plane + idx) = o;
  }
}

extern "C" void kernel_launch(void* const* d_in, const int* in_sizes, int n_in,
                              void* d_out, int out_size, void* d_ws, size_t ws_size,
                              hipStream_t stream) {
  (void)in_sizes; (void)n_in; (void)out_size;
  const float* x  = (const float*)d_in[0];
  const float* Qw = (const float*)d_in[1];
  const float* Kw = (const float*)d_in[2];
  const float* Vw = (const float*)d_in[3];
  float* out = (float*)d_out;
  char* ws = (char*)d_ws;

  const float scale = 0.04419417382415922f;  // 1/sqrt(512)

  // ---- big layout (unchunked): needs 188,235,776 B ----
  if (ws_size >= 188235776ULL) {
    double* stats = (double*)(ws + 256);
    u16* xnh  = (u16*)(ws + 16384);
    u16* xnl  = (u16*)(ws + 16793600);
    u16* Vt   = (u16*)(ws + 33570816);
    u16* W2th = (u16*)(ws + 34095104);
    u16* W2tl = (u16*)(ws + 34619392);
    u16* Qh   = (u16*)(ws + 35143680);
    u16* Ql   = (u16*)(ws + 35667968);
    u16* Kh   = (u16*)(ws + 36192256);
    u16* Kl   = (u16*)(ws + 36716544);
    u16* vt   = (u16*)(ws + 37240832);   // [16,512,1024] bf16  16 MB
    u16* th   = (u16*)(ws + 54018048);   // [16,1024,512] hi    16 MB
    u16* tl   = (u16*)(ws + 70795264);   // lo                  16 MB
    float* scomp = (float*)(ws + 87572480);   // [16,1024,1024] fp32  64 MB
    u16* attw = (u16*)(ws + 154681344);  // [16,1024,1024] bf16  32 MB

    bn_stats_f64<<<CC, 256, 0, stream>>>(x, stats);
    bn_apply_split<<<dim3(16, 8, 16), 256, 0, stream>>>(x, stats, xnh, xnl);
    conv_split<<<256, 256, 0, stream>>>(Qw, Qh, Ql);
    conv_split<<<256, 256, 0, stream>>>(Kw, Kh, Kl);
    trans_conv_v<<<dim3(8, 8), 256, 0, stream>>>(Vw, Vt);

    // W2t[c'][c] = sum_d K[c',d] Q[c,d]   (small; 128^2 kernel)
    mfma_nt<true, true, 2><<<dim3(4, 4, 1), 256, 0, stream>>>(
        Kh, Kl, 0, Qh, Ql, 0, W2th, W2tl, 0, 512, 512, 1.0f, nullptr, nullptr);

    // vt[b][d][token] = sum_c Vt[d,c] * xn[b,token,c]   128x256 tiles, 256 blocks
    mfma_pipe3<1, 2, 1, 2, 2><<<dim3(4, 4, 16), 512, 0, stream>>>(
        Vt, nullptr, 0, xnh, xnl, 524288, vt, nullptr, 524288, 1024, 512, 1.0f, nullptr, nullptr);

    // t[b,s,c'] = sum_c xn[b,s,c] * W2t[c'][c]   128x256 tiles, 256 blocks
    mfma_pipe3<2, 2, 2, 2, 2><<<dim3(2, 8, 16), 512, 0, stream>>>(
        xnh, xnl, 524288, W2th, W2tl, 0, th, tl, 524288, 512, 512, 1.0f, nullptr, nullptr);

    // scores[b,s,j] = scale * sum_c' t[b,s,c'] * xn[b,j,c']   128x256 tiles, 512 blocks
    mfma_pipe3<2, 2, 0, 2, 2><<<dim3(4, 8, 16), 512, 0, stream>>>(
        th, tl, 524288, xnh, xnl, 524288, scomp, nullptr, 1048576, 1024, 512, scale, nullptr, nullptr);

    softmax_chunk4<<<1024, 256, 0, stream>>>(scomp, attw, 1048576LL);

    // out[b,s,d] = sum_k attw[b,s,k] * vt[b,d,k] + xn residual   128x256 tiles, 256 blocks, 2/CU
    mfma_pipe3<1, 1, 3, 1, 4><<<dim3(2, 8, 16), 512, 0, stream>>>(
        attw, nullptr, 1048576, vt, nullptr, 524288,
        out, nullptr, 524288, 512, 1024, 1.0f, xnh, xnl);
    return;
  }

  // ---- fallback: proven chunked layout (85,475,328 B) ----
  double* stats = (double*)(ws + 256);
  u16* xnh  = (u16*)(ws + 16384);
  u16* xnl  = (u16*)(ws + 16793600);
  u16* Vt   = (u16*)(ws + 33570816);
  u16* W2th = (u16*)(ws + 34095104);
  u16* W2tl = (u16*)(ws + 34619392);
  u16* vt   = (u16*)(ws + 35143680);
  u16* th   = (u16*)(ws + 51920896);
  u16* tl   = (u16*)(ws + 56115200);
  float* scomp = (float*)(ws + 60309504);
  u16* attw = (u16*)(ws + 77086720);
  u16* Qh = (u16*)(ws + 51920896);
  u16* Ql = (u16*)(ws + 52445184);
  u16* Kh = (u16*)(ws + 52969472);
  u16* Kl = (u16*)(ws + 53493760);

  bn_stats_f64<<<CC, 256, 0, stream>>>(x, stats);
  bn_apply_split<<<dim3(16, 8, 16), 256, 0, stream>>>(x, stats, xnh, xnl);
  conv_split<<<256, 256, 0, stream>>>(Qw, Qh, Ql);
  conv_split<<<256, 256, 0, stream>>>(Kw, Kh, Kl);
  trans_conv_v<<<dim3(8, 8), 256, 0, stream>>>(Vw, Vt);

  mfma_nt<true, true, 2><<<dim3(4, 4, 1), 256, 0, stream>>>(
      Kh, Kl, 0, Qh, Ql, 0, W2th, W2tl, 0, 512, 512, 1.0f, nullptr, nullptr);

  mfma_nt<false, true, 1><<<dim3(8, 4, 16), 256, 0, stream>>>(
      Vt, nullptr, 0, xnh, xnl, 524288, vt, nullptr, 524288, 1024, 512, 1.0f, nullptr, nullptr);

  for (int ci = 0; ci < 4; ci++) {
    int s0c = ci * R;
    mfma_nt<true, true, 2><<<dim3(4, 2, 16), 256, 0, stream>>>(
        xnh + (long long)s0c * 512, xnl + (long long)s0c * 512, 524288,
        W2th, W2tl, 0, th, tl, 131072, 512, 512, 1.0f, nullptr, nullptr);
    mfma_nt<true, true, 0><<<dim3(8, 2, 16), 256, 0, stream>>>(
        th, tl, 131072, xnh, xnl, 524288, scomp, nullptr, 262144,
        1024, 512, scale, nullptr, nullptr);
    softmax_chunk<<<1024, 256, 0, stream>>>(scomp, attw, 262144LL);
    mfma_nt<false, false, 3><<<dim3(4, 2, 16), 256, 0, stream>>>(
        attw, nullptr, 262144, vt, nullptr, 524288,
        out + (long long)s0c * 512, nullptr, 524288, 512, 1024, 1.0f,
        xnh + (long long)s0c * 512, xnl + (long long)s0c * 512);
  }
}

// Round 6
// 294.768 us; speedup vs baseline: 1.1418x; 1.0695x over previous
//
#include <hip/hip_runtime.h>

typedef unsigned short u16;
typedef __bf16 bf16x8 __attribute__((ext_vector_type(8)));
typedef float f32x4 __attribute__((ext_vector_type(4)));

static constexpr int BB = 16;    // batch
static constexpr int CC = 512;   // channels
static constexpr int SS = 1024;  // seq
static constexpr int R  = 256;   // q-chunk rows (small-ws fallback path)

__device__ __forceinline__ u16 f2bf(float f) {
  __bf16 h = (__bf16)f; return __builtin_bit_cast(unsigned short, h);
}
__device__ __forceinline__ float bf2f(u16 u) {
  union { unsigned int i; float f; } v; v.i = ((unsigned int)u) << 16; return v.f;
}
__device__ __forceinline__ void split2(float v, u16& hi, u16& lo) {
  __bf16 h = (__bf16)v;
  float hf = (float)h;
  __bf16 l = (__bf16)(v - hf);
  hi = __builtin_bit_cast(unsigned short, h);
  lo = __builtin_bit_cast(unsigned short, l);
}

// async global->LDS, 16B per lane; LDS dest = wave-uniform base + lane*16
__device__ __forceinline__ void gld16(const u16* g, u16* l) {
  __builtin_amdgcn_global_load_lds(
      (const __attribute__((address_space(1))) void*)g,
      (__attribute__((address_space(3))) void*)l, 16, 0, 0);
}

// bijective XCD-chunked remap of a 3D grid (requires nwg % 8 == 0)
__device__ __forceinline__ void xcd_remap(int& bx, int& by, int& bz) {
  int gx = gridDim.x, gy = gridDim.y;
  int nwg = gx * gy * gridDim.z;
  int flat = (blockIdx.z * gy + blockIdx.y) * gx + blockIdx.x;
  int swz = ((nwg & 7) == 0) ? (flat & 7) * (nwg >> 3) + (flat >> 3) : flat;
  bx = swz % gx;
  int t1 = swz / gx;
  by = t1 % gy;
  bz = t1 / gy;
}

// ================= device bodies (shared-memory passed as pointer) =================

// ---- BatchNorm stats per channel over (B,S), fp64; dsh = 512 doubles ----
__device__ __forceinline__ void stats_body(const float* __restrict__ x, double* __restrict__ stats,
                                           int c, double* dsh) {
  double* sh = dsh;        // [256]
  double* sh2 = dsh + 256; // [256]
  double s = 0.0, s2 = 0.0;
  for (int n = threadIdx.x; n < BB * SS; n += 256) {
    int b = n >> 10, sp = n & (SS - 1);
    double v = (double)x[((long long)(b * CC + c)) * SS + sp];
    s += v; s2 += v * v;
  }
  sh[threadIdx.x] = s; sh2[threadIdx.x] = s2;
  __syncthreads();
  for (int off = 128; off > 0; off >>= 1) {
    if (threadIdx.x < off) { sh[threadIdx.x] += sh[threadIdx.x + off]; sh2[threadIdx.x] += sh2[threadIdx.x + off]; }
    __syncthreads();
  }
  if (threadIdx.x == 0) {
    double mean = sh[0] / 16384.0;
    double var = sh2[0] / 16384.0 - mean * mean;   // biased (torch BN)
    stats[c] = mean;
    stats[CC + c] = 1.0 / sqrt(var + 1e-5);
  }
}

// ---- normalize + transpose + split; tile = float[64][65] in shared ----
__device__ __forceinline__ void apply_body(const float* __restrict__ x, const double* __restrict__ stats,
                                           u16* __restrict__ xnh, u16* __restrict__ xnl,
                                           int bx, int by, int b, float (*tile)[65]) {
  const int s0 = bx * 64, c0 = by * 64;
  const int t = threadIdx.x & 63, rb = threadIdx.x >> 6;
#pragma unroll
  for (int r0 = 0; r0 < 64; r0 += 4) {
    int r = r0 + rb;
    int c = c0 + r;
    double v = (double)x[((long long)(b * CC + c)) * SS + s0 + t];
    tile[r][t] = (float)((v - stats[c]) * stats[CC + c]);
  }
  __syncthreads();
#pragma unroll
  for (int r0 = 0; r0 < 64; r0 += 4) {
    int r = r0 + rb;
    long long idx = ((long long)(b * SS + s0 + r)) * CC + c0 + t;
    u16 h, l; split2(tile[t][r], h, l);
    xnh[idx] = h; xnl[idx] = l;
  }
}

// ---- fp32 [n] -> bf16 hi/lo planes (per 256-thread block, rel block id) ----
__device__ __forceinline__ void conv_body(const float* __restrict__ src,
                                          u16* __restrict__ h, u16* __restrict__ l, int blk) {
  int i = (blk * 256 + threadIdx.x) * 4;
  float4 f = *reinterpret_cast<const float4*>(src + i);
  ushort4 H, L;
  split2(f.x, H.x, L.x); split2(f.y, H.y, L.y); split2(f.z, H.z, L.z); split2(f.w, H.w, L.w);
  *reinterpret_cast<ushort4*>(h + i) = H;
  *reinterpret_cast<ushort4*>(l + i) = L;
}

// ---- V fp32 [c][d] -> Vt bf16 [d][c]; tile = float[64][65] ----
__device__ __forceinline__ void trans_body(const float* __restrict__ V, u16* __restrict__ Vt,
                                           int bx, int by, float (*tile)[65]) {
  const int c0 = bx * 64, d0 = by * 64;
  const int t = threadIdx.x & 63, rb = threadIdx.x >> 6;
#pragma unroll
  for (int r0 = 0; r0 < 64; r0 += 4) {
    int r = r0 + rb;
    tile[r][t] = V[(long long)(c0 + r) * 512 + d0 + t];
  }
  __syncthreads();
#pragma unroll
  for (int r0 = 0; r0 < 64; r0 += 4) {
    int r = r0 + rb;
    Vt[(long long)(d0 + r) * 512 + c0 + t] = f2bf(tile[t][r]);
  }
}

// ---- MFMA NT GEMM body, 128x128 tile, BK=32, 256 threads (from proven mfma_nt) ----
// sm layout (u16): lah[4096] | lal[ASPLIT?4096:8] | lbh[4096] | lbl[BSPLIT?4096:8]
template <bool ASPLIT, bool BSPLIT, int OUTMODE>
__device__ __forceinline__ void nt_body(
    u16* __restrict__ sm, int bx, int by, int bz,
    const u16* __restrict__ Ah, const u16* __restrict__ Al, long long sA,
    const u16* __restrict__ Bh, const u16* __restrict__ Bl, long long sB,
    void* __restrict__ C, void* __restrict__ C2, long long sC,
    int N, int K, float scale, const u16* __restrict__ Rh, const u16* __restrict__ Rl) {
  u16* lah = sm;
  u16* lal = lah + 4096;
  u16* lbh = lal + (ASPLIT ? 4096 : 8);
  u16* lbl = lbh + 4096;

  const int tid = threadIdx.x;
  const int z = bz;
  const int m0 = by * 128, n0 = bx * 128;
  const int wave = tid >> 6, lane = tid & 63;
  const int wr = (wave >> 1) * 64, wc = (wave & 1) * 64;
  const int lrow = lane & 15, lquad = lane >> 4;
  const long long aB = (long long)z * sA, bB = (long long)z * sB;
  const int srow = tid >> 2, scg = (tid & 3) * 8;
  const int wofs = wave * 512;

  f32x4 acc[4][4];
#pragma unroll
  for (int i = 0; i < 4; i++)
#pragma unroll
    for (int j = 0; j < 4; j++) acc[i][j] = (f32x4){0.f, 0.f, 0.f, 0.f};

  for (int k0 = 0; k0 < K; k0 += 32) {
    const long long ar1 = aB + (long long)(m0 + srow) * K + k0 + scg;
    const long long ar2 = aB + (long long)(m0 + srow + 64) * K + k0 + scg;
    gld16(Ah + ar1, &lah[wofs]);
    gld16(Ah + ar2, &lah[wofs + 2048]);
    if constexpr (ASPLIT) {
      gld16(Al + ar1, &lal[wofs]);
      gld16(Al + ar2, &lal[wofs + 2048]);
    }
    const long long br1 = bB + (long long)(n0 + srow) * K + k0 + scg;
    const long long br2 = bB + (long long)(n0 + srow + 64) * K + k0 + scg;
    gld16(Bh + br1, &lbh[wofs]);
    gld16(Bh + br2, &lbh[wofs + 2048]);
    if constexpr (BSPLIT) {
      gld16(Bl + br1, &lbl[wofs]);
      gld16(Bl + br2, &lbl[wofs + 2048]);
    }
    __syncthreads();

    bf16x8 ah[4], al[ASPLIT ? 4 : 1], bh[4], bl[BSPLIT ? 4 : 1];
#pragma unroll
    for (int i = 0; i < 4; i++) {
      ah[i] = *reinterpret_cast<const bf16x8*>(&lah[(wr + i * 16 + lrow) * 32 + lquad * 8]);
      if constexpr (ASPLIT)
        al[i] = *reinterpret_cast<const bf16x8*>(&lal[(wr + i * 16 + lrow) * 32 + lquad * 8]);
      bh[i] = *reinterpret_cast<const bf16x8*>(&lbh[(wc + i * 16 + lrow) * 32 + lquad * 8]);
      if constexpr (BSPLIT)
        bl[i] = *reinterpret_cast<const bf16x8*>(&lbl[(wc + i * 16 + lrow) * 32 + lquad * 8]);
    }
#pragma unroll
    for (int i = 0; i < 4; i++)
#pragma unroll
      for (int j = 0; j < 4; j++) {
        f32x4 t = acc[i][j];
        if constexpr (ASPLIT) t = __builtin_amdgcn_mfma_f32_16x16x32_bf16(al[i], bh[j], t, 0, 0, 0);
        if constexpr (BSPLIT) t = __builtin_amdgcn_mfma_f32_16x16x32_bf16(ah[i], bl[j], t, 0, 0, 0);
        t = __builtin_amdgcn_mfma_f32_16x16x32_bf16(ah[i], bh[j], t, 0, 0, 0);
        acc[i][j] = t;
      }
    __syncthreads();
  }

  const long long zC = (long long)z * sC;
#pragma unroll
  for (int i = 0; i < 4; i++) {
    int rl_ = wr + i * 16 + lquad * 4;
#pragma unroll
    for (int j = 0; j < 4; j++) {
      int col = n0 + wc + j * 16 + lrow;
#pragma unroll
      for (int r = 0; r < 4; r++) {
        long long idx = zC + (long long)(m0 + rl_ + r) * N + col;
        float val = acc[i][j][r];
        if constexpr (OUTMODE == 0) {
          reinterpret_cast<float*>(C)[idx] = val * scale;
        } else if constexpr (OUTMODE == 1) {
          reinterpret_cast<u16*>(C)[idx] = f2bf(val);
        } else if constexpr (OUTMODE == 2) {
          u16 h, l; split2(val, h, l);
          reinterpret_cast<u16*>(C)[idx] = h;
          reinterpret_cast<u16*>(C2)[idx] = l;
        } else {
          reinterpret_cast<float*>(C)[idx] = val + bf2f(Rh[idx]) + bf2f(Rl[idx]);
        }
      }
    }
  }
}

// ---- pipelined MFMA NT GEMM body: BM x 256 tile, BK=32, 8 waves, dbuf LDS ----
// Proven R3 schedule: T2 src-swizzle, per-phase barriers + lgkmcnt(0) + setprio,
// staging in phases 0/1, vmcnt(0) drain at last phase. Bit-identical accumulation
// order (al*bh, ah*bl, ah*bh; k ascending).
// sm layout (u16): la[2][APL*BM*32] | lb[2][BPL*256*32]
template <int BM, int APL, int BPL, int OUTMODE, int PHASES>
__device__ __forceinline__ void pipe_body(
    u16* __restrict__ sm, int bx, int by, int bz,
    const u16* __restrict__ Ah, const u16* __restrict__ Al, long long sA,
    const u16* __restrict__ Bh, const u16* __restrict__ Bl, long long sB,
    void* __restrict__ C, void* __restrict__ C2, long long sC,
    int N, int K, float scale, const u16* __restrict__ Rh, const u16* __restrict__ Rl) {
  constexpr int MI = BM / 32;
  constexpr int IPP = MI / PHASES;
  constexpr int LA1 = APL * BM * 32;   // one A buffer, u16 units
  constexpr int LB1 = BPL * 256 * 32;
  u16* la = sm;            // [2][LA1]
  u16* lb = sm + 2 * LA1;  // [2][LB1]

  const int tid = threadIdx.x;
  const int m0 = by * BM, n0 = bx * 256;
  const int wave = tid >> 6, lane = tid & 63;
  const int wr = (wave >> 2) * (BM / 2), wc = (wave & 3) * 64;  // 2M x 4N waves
  const int lrow = lane & 15, lquad = lane >> 4;
  const long long aB = (long long)bz * sA + (long long)m0 * K;
  const long long bB = (long long)bz * sB + (long long)n0 * K;
  const int srow = tid >> 2;                                    // 0..127
  const int scg = ((tid & 3) ^ ((srow >> 1) & 3)) * 8;          // swizzled source chunk
  const int wofs = wave * 512;

  f32x4 acc[MI][4];
#pragma unroll
  for (int i = 0; i < MI; i++)
#pragma unroll
    for (int j = 0; j < 4; j++) acc[i][j] = (f32x4){0.f, 0.f, 0.f, 0.f};

  auto stageA = [&](int buf, int k0) {
#pragma unroll
    for (int pl = 0; pl < APL; ++pl) {
      const u16* src = pl ? Al : Ah;
      gld16(src + aB + (long long)srow * K + k0 + scg, &la[buf * LA1 + pl * BM * 32 + wofs]);
      if constexpr (BM == 256)
        gld16(src + aB + (long long)(srow + 128) * K + k0 + scg,
              &la[buf * LA1 + pl * BM * 32 + 4096 + wofs]);
    }
  };
  auto stageB = [&](int buf, int k0) {
#pragma unroll
    for (int pl = 0; pl < BPL; ++pl) {
      const u16* src = pl ? Bl : Bh;
      gld16(src + bB + (long long)srow * K + k0 + scg, &lb[buf * LB1 + pl * 256 * 32 + wofs]);
      gld16(src + bB + (long long)(srow + 128) * K + k0 + scg,
            &lb[buf * LB1 + pl * 256 * 32 + 4096 + wofs]);
    }
  };
  auto rdA = [&](int buf, int pl, int row) -> bf16x8 {
    return *reinterpret_cast<const bf16x8*>(
        &la[buf * LA1 + pl * BM * 32 + row * 32 + (lquad ^ ((row >> 1) & 3)) * 8]);
  };
  auto rdB = [&](int buf, int pl, int row) -> bf16x8 {
    return *reinterpret_cast<const bf16x8*>(
        &lb[buf * LB1 + pl * 256 * 32 + row * 32 + (lquad ^ ((row >> 1) & 3)) * 8]);
  };

  // prologue: stage K-tile 0 into buf 0
  stageA(0, 0);
  stageB(0, 0);
  asm volatile("s_waitcnt vmcnt(0)" ::: "memory");
  __builtin_amdgcn_s_barrier();

  const int nkt = K >> 5;
  bf16x8 bh_[4], bl_[BPL == 2 ? 4 : 1];

  for (int kt = 0; kt < nkt; ++kt) {
    const int cur = kt & 1;
    const int nk0 = (kt + 1) << 5;
    const bool pf = (kt + 1) < nkt;

#pragma unroll
    for (int p = 0; p < PHASES; ++p) {
      bf16x8 a_h[IPP], a_l[IPP];
#pragma unroll
      for (int ii = 0; ii < IPP; ++ii) {
        int row = wr + (p * IPP + ii) * 16 + lrow;
        a_h[ii] = rdA(cur, 0, row);
        if constexpr (APL == 2) a_l[ii] = rdA(cur, 1, row);
      }
      if (p == 0) {
#pragma unroll
        for (int j = 0; j < 4; ++j) {
          int row = wc + j * 16 + lrow;
          bh_[j] = rdB(cur, 0, row);
          if constexpr (BPL == 2) bl_[j] = rdB(cur, 1, row);
        }
      }
      if (pf) {
        if constexpr (PHASES == 1) {
          stageA(cur ^ 1, nk0);
          stageB(cur ^ 1, nk0);
        } else {
          if (p == 0) stageA(cur ^ 1, nk0);
          else if (p == 1) stageB(cur ^ 1, nk0);
        }
      }
      __builtin_amdgcn_sched_barrier(0);
      __builtin_amdgcn_s_barrier();
      asm volatile("s_waitcnt lgkmcnt(0)" ::: "memory");
      __builtin_amdgcn_sched_barrier(0);
      __builtin_amdgcn_s_setprio(1);
#pragma unroll
      for (int ii = 0; ii < IPP; ++ii) {
        int i = p * IPP + ii;
#pragma unroll
        for (int j = 0; j < 4; ++j) {
          f32x4 t = acc[i][j];
          if constexpr (APL == 2) t = __builtin_amdgcn_mfma_f32_16x16x32_bf16(a_l[ii], bh_[j], t, 0, 0, 0);
          if constexpr (BPL == 2) t = __builtin_amdgcn_mfma_f32_16x16x32_bf16(a_h[ii], bl_[j], t, 0, 0, 0);
          t = __builtin_amdgcn_mfma_f32_16x16x32_bf16(a_h[ii], bh_[j], t, 0, 0, 0);
          acc[i][j] = t;
        }
      }
      __builtin_amdgcn_s_setprio(0);
      if (p == PHASES - 1) asm volatile("s_waitcnt vmcnt(0)" ::: "memory");
      __builtin_amdgcn_s_barrier();
    }
  }

  const long long zC = (long long)bz * sC;
#pragma unroll
  for (int i = 0; i < MI; i++) {
    int rl_ = wr + i * 16 + lquad * 4;
#pragma unroll
    for (int j = 0; j < 4; j++) {
      int col = n0 + wc + j * 16 + lrow;
#pragma unroll
      for (int r = 0; r < 4; r++) {
        long long idx = zC + (long long)(m0 + rl_ + r) * N + col;
        float val = acc[i][j][r];
        if constexpr (OUTMODE == 0) {
          reinterpret_cast<float*>(C)[idx] = val * scale;
        } else if constexpr (OUTMODE == 1) {
          reinterpret_cast<u16*>(C)[idx] = f2bf(val);
        } else if constexpr (OUTMODE == 2) {
          u16 h, l; split2(val, h, l);
          reinterpret_cast<u16*>(C)[idx] = h;
          reinterpret_cast<u16*>(C2)[idx] = l;
        } else {
          reinterpret_cast<float*>(C)[idx] = val + bf2f(Rh[idx]) + bf2f(Rl[idx]);
        }
      }
    }
  }
}

// ================= standalone kernels (fallback path + big-path singles) =================

__global__ __launch_bounds__(256) void bn_stats_f64(const float* __restrict__ x, double* __restrict__ stats) {
  __shared__ __attribute__((aligned(16))) double dsh[512];
  stats_body(x, stats, blockIdx.x, dsh);
}

__global__ __launch_bounds__(256) void bn_apply_split(const float* __restrict__ x,
                                                      const double* __restrict__ stats,
                                                      u16* __restrict__ xnh, u16* __restrict__ xnl) {
  __shared__ __attribute__((aligned(16))) float tile[64][65];
  apply_body(x, stats, xnh, xnl, blockIdx.x, blockIdx.y, blockIdx.z, tile);
}

__global__ __launch_bounds__(256) void conv_split(const float* __restrict__ src,
                                                  u16* __restrict__ h, u16* __restrict__ l) {
  conv_body(src, h, l, blockIdx.x);
}

__global__ __launch_bounds__(256) void trans_conv_v(const float* __restrict__ V, u16* __restrict__ Vt) {
  __shared__ __attribute__((aligned(16))) float tile[64][65];
  trans_body(V, Vt, blockIdx.x, blockIdx.y, tile);
}

template <bool ASPLIT, bool BSPLIT, int OUTMODE>
__global__ __launch_bounds__(256) void mfma_nt(
    const u16* __restrict__ Ah, const u16* __restrict__ Al, long long sA,
    const u16* __restrict__ Bh, const u16* __restrict__ Bl, long long sB,
    void* __restrict__ C, void* __restrict__ C2, long long sC,
    int N, int K, float scale, const u16* __restrict__ Rh, const u16* __restrict__ Rl) {
  __shared__ __attribute__((aligned(16))) u16 sm[4096 + (ASPLIT ? 4096 : 8) + 4096 + (BSPLIT ? 4096 : 8)];
  int bx, by, bz;
  xcd_remap(bx, by, bz);
  nt_body<ASPLIT, BSPLIT, OUTMODE>(sm, bx, by, bz, Ah, Al, sA, Bh, Bl, sB, C, C2, sC, N, K, scale, Rh, Rl);
}

template <int BM, int APL, int BPL, int OUTMODE, int PHASES, int MW>
__global__ __launch_bounds__(512, MW) void mfma_pipe(
    const u16* __restrict__ Ah, const u16* __restrict__ Al, long long sA,
    const u16* __restrict__ Bh, const u16* __restrict__ Bl, long long sB,
    void* __restrict__ C, void* __restrict__ C2, long long sC,
    int N, int K, float scale, const u16* __restrict__ Rh, const u16* __restrict__ Rl) {
  __shared__ __attribute__((aligned(16))) u16 sm[2 * APL * BM * 32 + 2 * BPL * 256 * 32];
  int bx, by, bz;
  xcd_remap(bx, by, bz);
  pipe_body<BM, APL, BPL, OUTMODE, PHASES>(sm, bx, by, bz, Ah, Al, sA, Bh, Bl, sB, C, C2, sC, N, K, scale, Rh, Rl);
}

// ================= fused launch kernels (big path) =================

// L1: bn_stats (512 blocks) || conv_split Q (256) || conv_split K (256) || trans_conv_v (64)
__global__ __launch_bounds__(256) void fused_stats_prep(
    const float* __restrict__ x, double* __restrict__ stats,
    const float* __restrict__ Qw, u16* __restrict__ Qh, u16* __restrict__ Ql,
    const float* __restrict__ Kw, u16* __restrict__ Kh, u16* __restrict__ Kl,
    const float* __restrict__ Vw, u16* __restrict__ Vt) {
  __shared__ __attribute__((aligned(16))) char usm[16640];
  int f = blockIdx.x;
  if (f < 512) {
    stats_body(x, stats, f, (double*)usm);
  } else if (f < 768) {
    conv_body(Qw, Qh, Ql, f - 512);
  } else if (f < 1024) {
    conv_body(Kw, Kh, Kl, f - 768);
  } else {
    int g = f - 1024;
    trans_body(Vw, Vt, g & 7, g >> 3, (float(*)[65])usm);
  }
}

// L2: bn_apply (2048 blocks) || W2t GEMM (16 blocks)
__global__ __launch_bounds__(256) void fused_apply_w2t(
    const float* __restrict__ x, const double* __restrict__ stats,
    u16* __restrict__ xnh, u16* __restrict__ xnl,
    const u16* __restrict__ Qh, const u16* __restrict__ Ql,
    const u16* __restrict__ Kh, const u16* __restrict__ Kl,
    u16* __restrict__ W2th, u16* __restrict__ W2tl) {
  __shared__ __attribute__((aligned(16))) u16 sm[16384];  // 32 KB: W2t needs 32768 B; apply tile 16640 B
  int f = blockIdx.x;
  if (f < 2048) {
    apply_body(x, stats, xnh, xnl, f & 15, (f >> 4) & 7, f >> 7, (float(*)[65])sm);
  } else {
    int g = f - 2048;                       // 0..15; bijective xcd swizzle, nwg=16
    int swz = (g & 7) * 2 + (g >> 3);
    nt_body<true, true, 2>(sm, swz & 3, swz >> 2, 0, Kh, Kl, 0, Qh, Ql, 0,
                           W2th, W2tl, 0, 512, 512, 1.0f, nullptr, nullptr);
  }
}

// L3: vt GEMM (256 blocks) || t GEMM (256 blocks), both 512 threads
__global__ __launch_bounds__(512, 1) void fused_vt_t(
    const u16* __restrict__ Vt, const u16* __restrict__ xnh, const u16* __restrict__ xnl,
    const u16* __restrict__ W2th, const u16* __restrict__ W2tl,
    u16* __restrict__ vt, u16* __restrict__ th, u16* __restrict__ tl) {
  __shared__ __attribute__((aligned(16))) u16 sm[49152];  // 96 KB: t needs 98304 B; vt 81920 B
  int f = blockIdx.x;
  if (f < 256) {
    int swz = (f & 7) * 32 + (f >> 3);       // nwg=256
    int bx = swz & 3, by = (swz >> 2) & 3, bz = swz >> 4;   // grid (4,4,16)
    pipe_body<128, 1, 2, 1, 2>(sm, bx, by, bz, Vt, nullptr, 0, xnh, xnl, 524288,
                               vt, nullptr, 524288, 1024, 512, 1.0f, nullptr, nullptr);
  } else {
    int g = f - 256;
    int swz = (g & 7) * 32 + (g >> 3);       // nwg=256
    int bx = swz & 1, by = (swz >> 1) & 7, bz = swz >> 4;   // grid (2,8,16)
    pipe_body<128, 2, 2, 2, 2>(sm, bx, by, bz, xnh, xnl, 524288, W2th, W2tl, 0,
                               th, tl, 524288, 512, 512, 1.0f, nullptr, nullptr);
  }
}

// ---------------- softmax over batch axis: scomp fp32 -> attw bf16 (scalar, fallback) ----------------
__global__ __launch_bounds__(256) void softmax_chunk(const float* __restrict__ sc,
                                                     u16* __restrict__ w, long long plane) {
  long long idx = (long long)blockIdx.x * 256 + threadIdx.x;
  float v[16];
  float m = -3.4e38f;
#pragma unroll
  for (int b = 0; b < 16; b++) { v[b] = sc[(long long)b * plane + idx]; m = fmaxf(m, v[b]); }
  float s = 0.f;
#pragma unroll
  for (int b = 0; b < 16; b++) { v[b] = expf(v[b] - m); s += v[b]; }
  float inv = 1.f / s;
#pragma unroll
  for (int b = 0; b < 16; b++) w[(long long)b * plane + idx] = f2bf(v[b] * inv);
}

// ---------------- softmax over batch axis, float4-vectorized ----------------
__global__ __launch_bounds__(256) void softmax_chunk4(const float* __restrict__ sc,
                                                      u16* __restrict__ w, long long plane) {
  long long idx = ((long long)blockIdx.x * 256 + threadIdx.x) * 4;
  float4 v[16];
  float4 m = make_float4(-3.4e38f, -3.4e38f, -3.4e38f, -3.4e38f);
#pragma unroll
  for (int b = 0; b < 16; b++) {
    v[b] = *reinterpret_cast<const float4*>(sc + (long long)b * plane + idx);
    m.x = fmaxf(m.x, v[b].x); m.y = fmaxf(m.y, v[b].y);
    m.z = fmaxf(m.z, v[b].z); m.w = fmaxf(m.w, v[b].w);
  }
  float4 s = make_float4(0.f, 0.f, 0.f, 0.f);
#pragma unroll
  for (int b = 0; b < 16; b++) {
    v[b].x = expf(v[b].x - m.x); s.x += v[b].x;
    v[b].y = expf(v[b].y - m.y); s.y += v[b].y;
    v[b].z = expf(v[b].z - m.z); s.z += v[b].z;
    v[b].w = expf(v[b].w - m.w); s.w += v[b].w;
  }
  float4 inv = make_float4(1.f / s.x, 1.f / s.y, 1.f / s.z, 1.f / s.w);
#pragma unroll
  for (int b = 0; b < 16; b++) {
    ushort4 o;
    o.x = f2bf(v[b].x * inv.x); o.y = f2bf(v[b].y * inv.y);
    o.z = f2bf(v[b].z * inv.z); o.w = f2bf(v[b].w * inv.w);
    *reinterpret_cast<ushort4*>(w + (long long)b * plane + idx) = o;
  }
}

extern "C" void kernel_launch(void* const* d_in, const int* in_sizes, int n_in,
                              void* d_out, int out_size, void* d_ws, size_t ws_size,
                              hipStream_t stream) {
  (void)in_sizes; (void)n_in; (void)out_size;
  const float* x  = (const float*)d_in[0];
  const float* Qw = (const float*)d_in[1];
  const float* Kw = (const float*)d_in[2];
  const float* Vw = (const float*)d_in[3];
  float* out = (float*)d_out;
  char* ws = (char*)d_ws;

  const float scale = 0.04419417382415922f;  // 1/sqrt(512)

  // ---- big layout (unchunked): needs 188,235,776 B; 6 launches ----
  if (ws_size >= 188235776ULL) {
    double* stats = (double*)(ws + 256);
    u16* xnh  = (u16*)(ws + 16384);
    u16* xnl  = (u16*)(ws + 16793600);
    u16* Vt   = (u16*)(ws + 33570816);
    u16* W2th = (u16*)(ws + 34095104);
    u16* W2tl = (u16*)(ws + 34619392);
    u16* Qh   = (u16*)(ws + 35143680);
    u16* Ql   = (u16*)(ws + 35667968);
    u16* Kh   = (u16*)(ws + 36192256);
    u16* Kl   = (u16*)(ws + 36716544);
    u16* vt   = (u16*)(ws + 37240832);   // [16,512,1024] bf16  16 MB
    u16* th   = (u16*)(ws + 54018048);   // [16,1024,512] hi    16 MB
    u16* tl   = (u16*)(ws + 70795264);   // lo                  16 MB
    float* scomp = (float*)(ws + 87572480);   // [16,1024,1024] fp32  64 MB
    u16* attw = (u16*)(ws + 154681344);  // [16,1024,1024] bf16  32 MB

    // L1: stats || convQ || convK || transV
    fused_stats_prep<<<1088, 256, 0, stream>>>(x, stats, Qw, Qh, Ql, Kw, Kh, Kl, Vw, Vt);

    // L2: bn_apply || W2t
    fused_apply_w2t<<<2064, 256, 0, stream>>>(x, stats, xnh, xnl, Qh, Ql, Kh, Kl, W2th, W2tl);

    // L3: vt || t
    fused_vt_t<<<512, 512, 0, stream>>>(Vt, xnh, xnl, W2th, W2tl, vt, th, tl);

    // L4: scores[b,s,j] = scale * sum_c' t[b,s,c'] * xn[b,j,c']   256x256 tiles, 256 blocks
    mfma_pipe<256, 2, 2, 0, 4, 2><<<dim3(4, 4, 16), 512, 0, stream>>>(
        th, tl, 524288, xnh, xnl, 524288, scomp, nullptr, 1048576, 1024, 512, scale, nullptr, nullptr);

    // L5: softmax over batch axis
    softmax_chunk4<<<1024, 256, 0, stream>>>(scomp, attw, 1048576LL);

    // L6: out[b,s,d] = sum_k attw[b,s,k] * vt[b,d,k] + xn residual
    mfma_pipe<128, 1, 1, 3, 1, 4><<<dim3(2, 8, 16), 512, 0, stream>>>(
        attw, nullptr, 1048576, vt, nullptr, 524288,
        out, nullptr, 524288, 512, 1024, 1.0f, xnh, xnl);
    return;
  }

  // ---- fallback: proven chunked layout (85,475,328 B) ----
  double* stats = (double*)(ws + 256);
  u16* xnh  = (u16*)(ws + 16384);
  u16* xnl  = (u16*)(ws + 16793600);
  u16* Vt   = (u16*)(ws + 33570816);
  u16* W2th = (u16*)(ws + 34095104);
  u16* W2tl = (u16*)(ws + 34619392);
  u16* vt   = (u16*)(ws + 35143680);
  u16* th   = (u16*)(ws + 51920896);
  u16* tl   = (u16*)(ws + 56115200);
  float* scomp = (float*)(ws + 60309504);
  u16* attw = (u16*)(ws + 77086720);
  u16* Qh = (u16*)(ws + 51920896);
  u16* Ql = (u16*)(ws + 52445184);
  u16* Kh = (u16*)(ws + 52969472);
  u16* Kl = (u16*)(ws + 53493760);

  bn_stats_f64<<<CC, 256, 0, stream>>>(x, stats);
  bn_apply_split<<<dim3(16, 8, 16), 256, 0, stream>>>(x, stats, xnh, xnl);
  conv_split<<<256, 256, 0, stream>>>(Qw, Qh, Ql);
  conv_split<<<256, 256, 0, stream>>>(Kw, Kh, Kl);
  trans_conv_v<<<dim3(8, 8), 256, 0, stream>>>(Vw, Vt);

  mfma_nt<true, true, 2><<<dim3(4, 4, 1), 256, 0, stream>>>(
      Kh, Kl, 0, Qh, Ql, 0, W2th, W2tl, 0, 512, 512, 1.0f, nullptr, nullptr);

  mfma_nt<false, true, 1><<<dim3(8, 4, 16), 256, 0, stream>>>(
      Vt, nullptr, 0, xnh, xnl, 524288, vt, nullptr, 524288, 1024, 512, 1.0f, nullptr, nullptr);

  for (int ci = 0; ci < 4; ci++) {
    int s0c = ci * R;
    mfma_nt<true, true, 2><<<dim3(4, 2, 16), 256, 0, stream>>>(
        xnh + (long long)s0c * 512, xnl + (long long)s0c * 512, 524288,
        W2th, W2tl, 0, th, tl, 131072, 512, 512, 1.0f, nullptr, nullptr);
    mfma_nt<true, true, 0><<<dim3(8, 2, 16), 256, 0, stream>>>(
        th, tl, 131072, xnh, xnl, 524288, scomp, nullptr, 262144,
        1024, 512, scale, nullptr, nullptr);
    softmax_chunk<<<1024, 256, 0, stream>>>(scomp, attw, 262144LL);
    mfma_nt<false, false, 3><<<dim3(4, 2, 16), 256, 0, stream>>>(
        attw, nullptr, 262144, vt, nullptr, 524288,
        out + (long long)s0c * 512, nullptr, 524288, 512, 1024, 1.0f,
        xnh + (long long)s0c * 512, xnl + (long long)s0c * 512);
  }
}